// Round 5
// baseline (109.519 us; speedup 1.0000x reference)
//
#include <hip/hip_runtime.h>

constexpr int B = 256, N = 512, T = 200, TM1 = 199;
constexpr unsigned E_MAIN = (unsigned)B * N * TM1;        // 26,083,328 = 101,888 * 256
constexpr unsigned MAIN_BLOCKS = E_MAIN / 256;            // 101,888 exact
constexpr unsigned ITEM_BLOCKS = ((unsigned)B * TM1) / 256; // 199 exact
constexpr float MIN_HL = 15.0f / (24.0f * 60.0f);
constexpr float MAX_HL = 274.0f;
constexpr float INV_SPD = 1.0f / 86400.0f;

struct F3 { float x, y, z; };

__device__ __forceinline__ float hl_of(float s0, float s1, float s2,
                                       float th0, float th1, float th2) {
    float logit = fmaf(s0, th0, fmaf(s1, th1, s2 * th2));
    return fminf(fmaxf(exp2f(logit), MIN_HL), MAX_HL);
}

__device__ __forceinline__ float p_of(float hl, float dt_days) {
    float z = exp2f(-dt_days / hl);
    return 1.0f / (1.0f + __expf(-z));   // sigmoid(z), z in (0,1]
}

__global__ __launch_bounds__(256) void hlr_fused(
    const float* __restrict__ x0,
    const float* __restrict__ t,
    const int*   __restrict__ items,
    const float* __restrict__ stats,
    const float* __restrict__ theta,
    float* __restrict__ x_pred,     // (B*N, T)
    float* __restrict__ x_item,     // (B, TM1)
    float* __restrict__ half_life)  // (B*N, TM1)
{
    const float th0 = theta[0], th1 = theta[1], th2 = theta[2];
    const unsigned bid = blockIdx.x;

    if (bid < MAIN_BLOCKS) {
        // one (row, j) element per thread; lanes are consecutive flat elements
        const unsigned e   = bid * 256u + threadIdx.x;   // < E_MAIN
        const unsigned row = e / TM1;                    // magic-mul div
        const unsigned j   = e - row * TM1;              // 0..198
        const unsigned b   = row >> 9;                   // N = 512

        // stats[row, j, 0:3] — 12B at 12B lane stride: fully-coalesced dwordx3
        F3 s;
        __builtin_memcpy(&s, stats + (size_t)row * (T * 3) + (size_t)j * 3, sizeof(F3));

        const float* trow = t + (size_t)b * T;
        const float tj  = trow[j];
        const float tj1 = trow[j + 1];

        const float hl = hl_of(s.x, s.y, s.z, th0, th1, th2);
        const float p  = p_of(hl, (tj1 - tj) * INV_SPD);

        half_life[e] = hl;                                // flat (B*N, TM1)
        x_pred[(size_t)row * T + j + 1] = p;
        if (j == 0) x_pred[(size_t)row * T] = x0[row];
    } else {
        // x_item_pred: gather + recompute (50,944 threads)
        const int i = (int)(bid - MAIN_BLOCKS) * 256 + (int)threadIdx.x;  // < B*TM1
        const int b = i / TM1;
        const int j = i - b * TM1;
        const int n = items[(size_t)b * T + j + 1];

        F3 s;
        __builtin_memcpy(&s, stats + ((size_t)((size_t)b * N + n) * T + j) * 3, sizeof(F3));
        const float hl = hl_of(s.x, s.y, s.z, th0, th1, th2);
        const float dt = (t[(size_t)b * T + j + 1] - t[(size_t)b * T + j]) * INV_SPD;
        x_item[i] = p_of(hl, dt);
    }
}

extern "C" void kernel_launch(void* const* d_in, const int* in_sizes, int n_in,
                              void* d_out, int out_size, void* d_ws, size_t ws_size,
                              hipStream_t stream) {
    const float* x0    = (const float*)d_in[0];
    const float* t     = (const float*)d_in[1];
    const int*   items = (const int*)d_in[2];
    const float* stats = (const float*)d_in[3];
    const float* theta = (const float*)d_in[4];

    float* out = (float*)d_out;
    float* x_pred    = out;                                        // B*N*T
    float* x_item    = out + (size_t)B * N * T;                    // B*TM1
    float* half_life = out + (size_t)B * N * T + (size_t)B * TM1;  // B*N*TM1

    hlr_fused<<<MAIN_BLOCKS + ITEM_BLOCKS, 256, 0, stream>>>(
        x0, t, items, stats, theta, x_pred, x_item, half_life);
}